// Round 1
// baseline (382.192 us; speedup 1.0000x reference)
//
#include <hip/hip_runtime.h>
#include <hip/hip_bf16.h>

// ROI Align (torchvision semantics, aligned=False), fp32.
// features: (N=2, C=256, H=200, W=304) NCHW fp32
// boxes:    (R=1000, 5) fp32  [batch_idx, x1, y1, x2, y2] in image coords
// out:      (R, C, 7, 7) fp32
// spatial_scale = 0.25, sampling_ratio G = 2, output 7x7.
//
// One thread per output element, idx = ((r*C + c)*7 + ph)*7 + pw.
// A 64-lane wave covers one (roi,channel) 7x7 slice (+ part of next channel),
// so its 16 gather loads stay inside a ~few-KB contiguous-row region -> L1/L2
// friendly. Features (124.5 MB) fit in the 256 MB Infinity Cache, so cross-
// block re-reads are L3-absorbed.

constexpr int C_CH = 256;
constexpr int H_F  = 200;
constexpr int W_F  = 304;
constexpr int PH   = 7;
constexpr int PW   = 7;
constexpr float SCALE = 0.25f;

__global__ __launch_bounds__(256) void roi_align_kernel(
    const float* __restrict__ feat,
    const float* __restrict__ boxes,
    float* __restrict__ out,
    int total)
{
    int idx = blockIdx.x * 256 + threadIdx.x;
    if (idx >= total) return;

    int pw = idx % PW;
    int t  = idx / PW;
    int ph = t % PH;
    t /= PH;
    int c = t & (C_CH - 1);
    int r = t >> 8;

    const float* box = boxes + r * 5;
    int   b  = (int)box[0];
    float x1 = box[1] * SCALE;
    float y1 = box[2] * SCALE;
    float x2 = box[3] * SCALE;
    float y2 = box[4] * SCALE;
    float roi_w = fmaxf(x2 - x1, 1.0f);
    float roi_h = fmaxf(y2 - y1, 1.0f);
    float bin_w = roi_w * (1.0f / PW);
    float bin_h = roi_h * (1.0f / PH);

    const float* fp = feat + ((size_t)b * C_CH + c) * (H_F * W_F);

    float acc = 0.0f;
#pragma unroll
    for (int iy = 0; iy < 2; ++iy) {
        float y  = y1 + ((float)ph + (iy ? 0.75f : 0.25f)) * bin_h;
        bool  vy = (y >= -1.0f) && (y <= (float)H_F);
        float cy = fmaxf(y, 0.0f);
        int   ylr = (int)floorf(cy);
        int   yl, yh;
        float fy;
        if (ylr >= H_F - 1) { yl = H_F - 1; yh = H_F - 1; fy = 0.0f; }
        else                { yl = ylr;     yh = ylr + 1; fy = cy - (float)ylr; }
#pragma unroll
        for (int ix = 0; ix < 2; ++ix) {
            float x  = x1 + ((float)pw + (ix ? 0.75f : 0.25f)) * bin_w;
            bool  vx = (x >= -1.0f) && (x <= (float)W_F);
            float cx = fmaxf(x, 0.0f);
            int   xlr = (int)floorf(cx);
            int   xl, xh;
            float fx;
            if (xlr >= W_F - 1) { xl = W_F - 1; xh = W_F - 1; fx = 0.0f; }
            else                { xl = xlr;     xh = xlr + 1; fx = cx - (float)xlr; }

            if (vy && vx) {
                const float* row_l = fp + yl * W_F;
                const float* row_h = fp + yh * W_F;
                float vll = row_l[xl];
                float vlh = row_l[xh];
                float vhl = row_h[xl];
                float vhh = row_h[xh];
                float vlo = vll + fx * (vlh - vll);
                float vhi = vhl + fx * (vhh - vhl);
                acc += vlo + fy * (vhi - vlo);
            }
        }
    }
    out[idx] = acc * 0.25f;
}

extern "C" void kernel_launch(void* const* d_in, const int* in_sizes, int n_in,
                              void* d_out, int out_size, void* d_ws, size_t ws_size,
                              hipStream_t stream) {
    const float* feat  = (const float*)d_in[0];
    const float* boxes = (const float*)d_in[1];
    float* out = (float*)d_out;
    int total = out_size;  // R * C * 7 * 7
    int blocks = (total + 255) / 256;
    roi_align_kernel<<<blocks, 256, 0, stream>>>(feat, boxes, out, total);
}

// Round 2
// 350.345 us; speedup vs baseline: 1.0909x; 1.0909x over previous
//
#include <hip/hip_runtime.h>
#include <hip/hip_bf16.h>

// ROI Align (torchvision semantics), fp32, two-phase:
//   Phase 1: transpose features NCHW -> NHWC into d_ws (fully coalesced both
//            sides via 64x64 LDS tile transpose).
//   Phase 2: gather with lanes across channels. One 64-thread block handles
//            (roi, channel-group-of-64): every bilinear tap load is 64
//            consecutive floats (256 B, fully consumed). Results staged in
//            LDS so the final store is contiguous (keeps WRITE_SIZE at 49 MB).
// Fallback: if ws_size < 124.5 MB, launch the round-1 NCHW kernel.

constexpr int N_B  = 2;
constexpr int C_CH = 256;
constexpr int H_F  = 200;
constexpr int W_F  = 304;
constexpr int HW   = H_F * W_F;        // 60800 (= 64 * 950)
constexpr int PH   = 7;
constexpr int PW   = 7;
constexpr int CELLS = PH * PW;         // 49
constexpr float SCALE = 0.25f;

// ---------------- Phase 1: NCHW -> NHWC transpose ----------------
// Per batch n: in viewed (C=256, HW=60800), out viewed (HW, C).
// grid (HW/64=950, C/64=4, N=2), block 256.
__global__ __launch_bounds__(256) void transpose_nchw_nhwc(
    const float* __restrict__ in, float* __restrict__ out)
{
    __shared__ float tile[64][65];
    int tx = blockIdx.x * 64;          // along HW
    int ty = blockIdx.y * 64;          // along C
    int n  = blockIdx.z;
    const float* ip = in  + (size_t)n * C_CH * HW;
    float*       op = out + (size_t)n * HW * C_CH;

    int tidx = threadIdx.x & 63;
    int tidy = threadIdx.x >> 6;       // 0..3
#pragma unroll
    for (int j = 0; j < 16; ++j) {
        int r = j * 4 + tidy;          // 0..63 (C-dim row)
        tile[r][tidx] = ip[(size_t)(ty + r) * HW + tx + tidx];
    }
    __syncthreads();
#pragma unroll
    for (int j = 0; j < 16; ++j) {
        int r = j * 4 + tidy;          // 0..63 (HW-dim row of output)
        op[(size_t)(tx + r) * C_CH + ty + tidx] = tile[tidx][r];
    }
}

// ---------------- Phase 2: ROI gather from NHWC ----------------
// block = 64 threads = 64 consecutive channels; blockIdx.x = r*4 + cgroup.
__global__ __launch_bounds__(64) void roi_gather_nhwc(
    const float* __restrict__ feat_nhwc,
    const float* __restrict__ boxes,
    float* __restrict__ out, int R)
{
    __shared__ float buf[64 * CELLS];  // 12.25 KB
    int blk  = blockIdx.x;
    int r    = blk >> 2;
    int cg   = blk & 3;
    if (r >= R) return;
    int lane = threadIdx.x;

    const float* box = boxes + r * 5;
    int   b  = (int)box[0];
    float x1 = box[1] * SCALE;
    float y1 = box[2] * SCALE;
    float x2 = box[3] * SCALE;
    float y2 = box[4] * SCALE;
    float bin_w = fmaxf(x2 - x1, 1.0f) * (1.0f / PW);
    float bin_h = fmaxf(y2 - y1, 1.0f) * (1.0f / PH);

    // per-lane channel base: batch plane + channel offset
    const float* fb = feat_nhwc + (size_t)b * HW * C_CH + cg * 64 + lane;

    for (int ph = 0; ph < PH; ++ph) {
        // y geometry for the 2 y-samples (wave-uniform)
        int   yl[2], yh[2];
        float fy[2];
        bool  vy[2];
#pragma unroll
        for (int iy = 0; iy < 2; ++iy) {
            float y = y1 + ((float)ph + (iy ? 0.75f : 0.25f)) * bin_h;
            vy[iy] = (y >= -1.0f) && (y <= (float)H_F);
            float cy = fmaxf(y, 0.0f);
            int ylr = (int)floorf(cy);
            if (ylr >= H_F - 1) { yl[iy] = H_F - 1; yh[iy] = H_F - 1; fy[iy] = 0.0f; }
            else                { yl[iy] = ylr;     yh[iy] = ylr + 1; fy[iy] = cy - (float)ylr; }
        }
        for (int pw = 0; pw < PW; ++pw) {
            float acc = 0.0f;
#pragma unroll
            for (int ix = 0; ix < 2; ++ix) {
                float x = x1 + ((float)pw + (ix ? 0.75f : 0.25f)) * bin_w;
                bool vx = (x >= -1.0f) && (x <= (float)W_F);
                float cx = fmaxf(x, 0.0f);
                int xlr = (int)floorf(cx);
                int xl, xh;
                float fx;
                if (xlr >= W_F - 1) { xl = W_F - 1; xh = W_F - 1; fx = 0.0f; }
                else                { xl = xlr;     xh = xlr + 1; fx = cx - (float)xlr; }
#pragma unroll
                for (int iy = 0; iy < 2; ++iy) {
                    if (vy[iy] && vx) {
                        int ol = (yl[iy] * W_F + xl) * C_CH;
                        int oh = (yh[iy] * W_F + xh) * C_CH;  // placeholder; need 4 taps
                        // 4 taps: (yl,xl) (yl,xh) (yh,xl) (yh,xh)
                        float vll = fb[(size_t)(yl[iy] * W_F + xl) * C_CH];
                        float vlh = fb[(size_t)(yl[iy] * W_F + xh) * C_CH];
                        float vhl = fb[(size_t)(yh[iy] * W_F + xl) * C_CH];
                        float vhh = fb[(size_t)(yh[iy] * W_F + xh) * C_CH];
                        float vlo = vll + fx * (vlh - vll);
                        float vhi = vhl + fx * (vhh - vhl);
                        acc += vlo + fy[iy] * (vhi - vlo);
                        (void)ol; (void)oh;
                    }
                }
            }
            buf[lane * CELLS + ph * PW + pw] = acc * 0.25f;
        }
    }
    __syncthreads();
    float* ob = out + ((size_t)r * C_CH + cg * 64) * CELLS;  // 3136 contiguous floats
#pragma unroll
    for (int i = 0; i < CELLS; ++i) {
        ob[i * 64 + lane] = buf[i * 64 + lane];
    }
}

// ---------------- Fallback (round-1 kernel, NCHW direct) ----------------
__global__ __launch_bounds__(256) void roi_align_fallback(
    const float* __restrict__ feat,
    const float* __restrict__ boxes,
    float* __restrict__ out, int total)
{
    int idx = blockIdx.x * 256 + threadIdx.x;
    if (idx >= total) return;
    int pw = idx % PW;
    int t  = idx / PW;
    int ph = t % PH;
    t /= PH;
    int c = t & (C_CH - 1);
    int r = t >> 8;

    const float* box = boxes + r * 5;
    int   b  = (int)box[0];
    float x1 = box[1] * SCALE;
    float y1 = box[2] * SCALE;
    float x2 = box[3] * SCALE;
    float y2 = box[4] * SCALE;
    float bin_w = fmaxf(x2 - x1, 1.0f) * (1.0f / PW);
    float bin_h = fmaxf(y2 - y1, 1.0f) * (1.0f / PH);
    const float* fp = feat + ((size_t)b * C_CH + c) * HW;

    float acc = 0.0f;
#pragma unroll
    for (int iy = 0; iy < 2; ++iy) {
        float y = y1 + ((float)ph + (iy ? 0.75f : 0.25f)) * bin_h;
        bool vy = (y >= -1.0f) && (y <= (float)H_F);
        float cy = fmaxf(y, 0.0f);
        int ylr = (int)floorf(cy);
        int yl, yh; float fy;
        if (ylr >= H_F - 1) { yl = H_F - 1; yh = H_F - 1; fy = 0.0f; }
        else                { yl = ylr;     yh = ylr + 1; fy = cy - (float)ylr; }
#pragma unroll
        for (int ix = 0; ix < 2; ++ix) {
            float x = x1 + ((float)pw + (ix ? 0.75f : 0.25f)) * bin_w;
            bool vx = (x >= -1.0f) && (x <= (float)W_F);
            float cx = fmaxf(x, 0.0f);
            int xlr = (int)floorf(cx);
            int xl, xh; float fx;
            if (xlr >= W_F - 1) { xl = W_F - 1; xh = W_F - 1; fx = 0.0f; }
            else                { xl = xlr;     xh = xlr + 1; fx = cx - (float)xlr; }
            if (vy && vx) {
                const float* rl = fp + yl * W_F;
                const float* rh = fp + yh * W_F;
                float vll = rl[xl], vlh = rl[xh], vhl = rh[xl], vhh = rh[xh];
                float vlo = vll + fx * (vlh - vll);
                float vhi = vhl + fx * (vhh - vhl);
                acc += vlo + fy * (vhi - vlo);
            }
        }
    }
    out[idx] = acc * 0.25f;
}

extern "C" void kernel_launch(void* const* d_in, const int* in_sizes, int n_in,
                              void* d_out, int out_size, void* d_ws, size_t ws_size,
                              hipStream_t stream) {
    const float* feat  = (const float*)d_in[0];
    const float* boxes = (const float*)d_in[1];
    float* out = (float*)d_out;
    int R = in_sizes[1] / 5;

    size_t need = (size_t)N_B * C_CH * HW * sizeof(float);  // 124.5 MB
    if (ws_size >= need) {
        float* nhwc = (float*)d_ws;
        dim3 tg(HW / 64, C_CH / 64, N_B);   // (950, 4, 2)
        transpose_nchw_nhwc<<<tg, 256, 0, stream>>>(feat, nhwc);
        roi_gather_nhwc<<<R * 4, 64, 0, stream>>>(nhwc, boxes, out, R);
    } else {
        int total = out_size;
        roi_align_fallback<<<(total + 255) / 256, 256, 0, stream>>>(feat, boxes, out, total);
    }
}

// Round 3
// 293.818 us; speedup vs baseline: 1.3008x; 1.1924x over previous
//
#include <hip/hip_runtime.h>
#include <hip/hip_bf16.h>

// ROI Align (torchvision semantics), fp32, two-phase:
//   Phase 1: NCHW -> NHWC transpose (float4 global loads AND stores, LDS tile).
//   Phase 2: gather; block = 256 thr = 4 waves = (roi, 128-channel half).
//            Lane covers 2 consecutive channels (float2 taps = 512 B/wave).
//            Waves split the 49 cells round-robin; results staged in LDS so
//            the final store is one contiguous 25 KB block (WRITE stays 49 MB).
// Fallback: if ws_size < 124.5 MB, round-1 NCHW kernel.

constexpr int N_B  = 2;
constexpr int C_CH = 256;
constexpr int H_F  = 200;
constexpr int W_F  = 304;
constexpr int HW   = H_F * W_F;        // 60800 = 64 * 950
constexpr int PH   = 7;
constexpr int PW   = 7;
constexpr int CELLS = PH * PW;         // 49
constexpr float SCALE = 0.25f;

// ---------------- Phase 1: NCHW -> NHWC transpose ----------------
// grid (HW/64=950, C/64=4, N=2), block 256. 16B/lane on both global sides.
__global__ __launch_bounds__(256) void transpose_nchw_nhwc(
    const float* __restrict__ in, float* __restrict__ out)
{
    __shared__ float tile[64][65];     // [c][hw], pad -> 2-way banks (free)
    int tx = blockIdx.x * 64;          // HW base
    int ty = blockIdx.y * 64;          // C base
    int n  = blockIdx.z;
    const float* ip = in  + (size_t)n * C_CH * HW;
    float*       op = out + (size_t)n * HW * C_CH;

    int w4 = threadIdx.x & 15;         // HW quad index
    int cr = threadIdx.x >> 4;         // 0..15
#pragma unroll
    for (int p = 0; p < 4; ++p) {
        int c = p * 16 + cr;
        float4 v = *(const float4*)&ip[(size_t)(ty + c) * HW + tx + 4 * w4];
        tile[c][4 * w4 + 0] = v.x;
        tile[c][4 * w4 + 1] = v.y;
        tile[c][4 * w4 + 2] = v.z;
        tile[c][4 * w4 + 3] = v.w;
    }
    __syncthreads();
    int cq = threadIdx.x & 15;         // channel quad index
    int hr = threadIdx.x >> 4;         // 0..15
#pragma unroll
    for (int p = 0; p < 4; ++p) {
        int hw = p * 16 + hr;
        float4 v;
        v.x = tile[4 * cq + 0][hw];
        v.y = tile[4 * cq + 1][hw];
        v.z = tile[4 * cq + 2][hw];
        v.w = tile[4 * cq + 3][hw];
        *(float4*)&op[(size_t)(tx + hw) * C_CH + ty + 4 * cq] = v;
    }
}

// ---------------- Phase 2: ROI gather from NHWC ----------------
// blockIdx.x = r*2 + cg (cg = which 128-channel half). 256 thr = 4 waves.
__global__ __launch_bounds__(256) void roi_gather_nhwc(
    const float* __restrict__ feat_nhwc,
    const float* __restrict__ boxes,
    float* __restrict__ out, int R)
{
    __shared__ alignas(16) float lds[128 * CELLS];   // 6272 floats = 24.5 KB
    int blk = blockIdx.x;
    int r   = blk >> 1;
    int cg  = blk & 1;
    if (r >= R) return;
    int tid  = threadIdx.x;
    int wave = tid >> 6;
    int lane = tid & 63;

    const float* box = boxes + r * 5;
    int   b  = (int)box[0];
    float x1 = box[1] * SCALE;
    float y1 = box[2] * SCALE;
    float x2 = box[3] * SCALE;
    float y2 = box[4] * SCALE;
    float bin_w = fmaxf(x2 - x1, 1.0f) * (1.0f / PW);
    float bin_h = fmaxf(y2 - y1, 1.0f) * (1.0f / PH);

    // lane covers channels (cg*128 + 2*lane, +1)
    const float* fb = feat_nhwc + (size_t)b * HW * C_CH + cg * 128 + 2 * lane;

    for (int cell = wave; cell < CELLS; cell += 4) {
        int ph = cell / PW;
        int pw = cell - ph * PW;

        float ax = 0.0f, ay = 0.0f;   // float2 accumulator
#pragma unroll
        for (int iy = 0; iy < 2; ++iy) {
            float y = y1 + ((float)ph + (iy ? 0.75f : 0.25f)) * bin_h;
            bool vy = (y >= -1.0f) && (y <= (float)H_F);
            float cy = fmaxf(y, 0.0f);
            int ylr = (int)floorf(cy);
            int yl, yh; float fy;
            if (ylr >= H_F - 1) { yl = H_F - 1; yh = H_F - 1; fy = 0.0f; }
            else                { yl = ylr;     yh = ylr + 1; fy = cy - (float)ylr; }
#pragma unroll
            for (int ix = 0; ix < 2; ++ix) {
                float x = x1 + ((float)pw + (ix ? 0.75f : 0.25f)) * bin_w;
                bool vx = (x >= -1.0f) && (x <= (float)W_F);
                float cx = fmaxf(x, 0.0f);
                int xlr = (int)floorf(cx);
                int xl, xh; float fx;
                if (xlr >= W_F - 1) { xl = W_F - 1; xh = W_F - 1; fx = 0.0f; }
                else                { xl = xlr;     xh = xlr + 1; fx = cx - (float)xlr; }

                if (vy && vx) {
                    float2 vll = *(const float2*)(fb + (size_t)(yl * W_F + xl) * C_CH);
                    float2 vlh = *(const float2*)(fb + (size_t)(yl * W_F + xh) * C_CH);
                    float2 vhl = *(const float2*)(fb + (size_t)(yh * W_F + xl) * C_CH);
                    float2 vhh = *(const float2*)(fb + (size_t)(yh * W_F + xh) * C_CH);
                    float lox = vll.x + fx * (vlh.x - vll.x);
                    float loy = vll.y + fx * (vlh.y - vll.y);
                    float hix = vhl.x + fx * (vhh.x - vhl.x);
                    float hiy = vhl.y + fx * (vhh.y - vhl.y);
                    ax += lox + fy * (hix - lox);
                    ay += loy + fy * (hiy - loy);
                }
            }
        }
        lds[(2 * lane)     * CELLS + cell] = ax * 0.25f;
        lds[(2 * lane + 1) * CELLS + cell] = ay * 0.25f;
    }
    __syncthreads();

    // contiguous 6272-float block: out[r][cg*128 .. cg*128+127][7][7]
    const float4* src = (const float4*)lds;
    float4* dst = (float4*)(out + (size_t)r * (C_CH * CELLS) + (size_t)cg * 128 * CELLS);
#pragma unroll
    for (int i = tid; i < (128 * CELLS) / 4; i += 256) {
        dst[i] = src[i];
    }
}

// ---------------- Fallback (round-1 kernel, NCHW direct) ----------------
__global__ __launch_bounds__(256) void roi_align_fallback(
    const float* __restrict__ feat,
    const float* __restrict__ boxes,
    float* __restrict__ out, int total)
{
    int idx = blockIdx.x * 256 + threadIdx.x;
    if (idx >= total) return;
    int pw = idx % PW;
    int t  = idx / PW;
    int ph = t % PH;
    t /= PH;
    int c = t & (C_CH - 1);
    int r = t >> 8;

    const float* box = boxes + r * 5;
    int   b  = (int)box[0];
    float x1 = box[1] * SCALE;
    float y1 = box[2] * SCALE;
    float x2 = box[3] * SCALE;
    float y2 = box[4] * SCALE;
    float bin_w = fmaxf(x2 - x1, 1.0f) * (1.0f / PW);
    float bin_h = fmaxf(y2 - y1, 1.0f) * (1.0f / PH);
    const float* fp = feat + ((size_t)b * C_CH + c) * HW;

    float acc = 0.0f;
#pragma unroll
    for (int iy = 0; iy < 2; ++iy) {
        float y = y1 + ((float)ph + (iy ? 0.75f : 0.25f)) * bin_h;
        bool vy = (y >= -1.0f) && (y <= (float)H_F);
        float cy = fmaxf(y, 0.0f);
        int ylr = (int)floorf(cy);
        int yl, yh; float fy;
        if (ylr >= H_F - 1) { yl = H_F - 1; yh = H_F - 1; fy = 0.0f; }
        else                { yl = ylr;     yh = ylr + 1; fy = cy - (float)ylr; }
#pragma unroll
        for (int ix = 0; ix < 2; ++ix) {
            float x = x1 + ((float)pw + (ix ? 0.75f : 0.25f)) * bin_w;
            bool vx = (x >= -1.0f) && (x <= (float)W_F);
            float cx = fmaxf(x, 0.0f);
            int xlr = (int)floorf(cx);
            int xl, xh; float fx;
            if (xlr >= W_F - 1) { xl = W_F - 1; xh = W_F - 1; fx = 0.0f; }
            else                { xl = xlr;     xh = xlr + 1; fx = cx - (float)xlr; }
            if (vy && vx) {
                const float* rl = fp + yl * W_F;
                const float* rh = fp + yh * W_F;
                float vll = rl[xl], vlh = rl[xh], vhl = rh[xl], vhh = rh[xh];
                float vlo = vll + fx * (vlh - vll);
                float vhi = vhl + fx * (vhh - vhl);
                acc += vlo + fy * (vhi - vlo);
            }
        }
    }
    out[idx] = acc * 0.25f;
}

extern "C" void kernel_launch(void* const* d_in, const int* in_sizes, int n_in,
                              void* d_out, int out_size, void* d_ws, size_t ws_size,
                              hipStream_t stream) {
    const float* feat  = (const float*)d_in[0];
    const float* boxes = (const float*)d_in[1];
    float* out = (float*)d_out;
    int R = in_sizes[1] / 5;

    size_t need = (size_t)N_B * C_CH * HW * sizeof(float);  // 124.5 MB
    if (ws_size >= need) {
        float* nhwc = (float*)d_ws;
        dim3 tg(HW / 64, C_CH / 64, N_B);   // (950, 4, 2)
        transpose_nchw_nhwc<<<tg, 256, 0, stream>>>(feat, nhwc);
        roi_gather_nhwc<<<R * 2, 256, 0, stream>>>(nhwc, boxes, out, R);
    } else {
        int total = out_size;
        roi_align_fallback<<<(total + 255) / 256, 256, 0, stream>>>(feat, boxes, out, total);
    }
}